// Round 14
// baseline (21.315 us; speedup 1.0000x reference)
//
#include <hip/hip_runtime.h>

// TransE 'rhs': pred[b,n] = MARGIN - ||(s+r)[b] - e[n]||_2. B=32,N=200k,D=64 fp32.
//
// R13 post-mortem: R12==R13 at ~20.2us despite 2x waves/CU -> not issuer-
// bound. Grid 782 = 3*256+14: 14 CUs host 4 blocks vs 3 -> 33% per-CU work
// imbalance; 20.2 ~= 15.2 * 4/3. Explains R11 (25.5: 4th block serialized)
// too. R14: grid 768 = 3/CU exactly; 6250 tiles = 768*8 + 106; each block
// does 8 contiguous tiles (clean 1KB-row stores preserved); blocks 0..105
// take one extra far tile (6144+b) appended to wave0's pipeline (5-tile leg,
// same counted vmcnt(8) rotation). Body = R12 verbatim otherwise.

#define MARGIN 9.0f
#define EXTRA 106                  // 6250 - 768*8
#define NT_MAIN 6144               // 768*8

typedef __attribute__((ext_vector_type(8)))  short bf16x8;
typedef __attribute__((ext_vector_type(16))) float f32x16;
typedef __attribute__((ext_vector_type(4)))  unsigned int u32x4;

typedef __attribute__((address_space(3))) void        lds_vp;
typedef __attribute__((address_space(1))) const void  glb_vp;

__device__ __forceinline__ unsigned eswz(unsigned p) {   // in-row involution
    return p ^ (((p >> 8) & 15u) << 4);
}

__global__ __launch_bounds__(128, 3)
void transe14(const float* __restrict__ s_emb,
              const float* __restrict__ rel_emb,
              const float* __restrict__ emb_e,
              float* __restrict__ out, int N)
{
    __shared__ __align__(16) char lds[36864];   // 32KB bufs + 4KB oE overlay
    const int t = threadIdx.x, w = t >> 6, lane = t & 63;
    const int m = lane & 31, h = lane >> 5;
    char* const b0 = lds + w * 16384;
    char* const b1 = b0 + 8192;
    const long T0 = (long)blockIdx.x * 8 + w * 4;    // wave's 4 main tiles
    const bool hv = (w == 0) && (blockIdx.x < EXTRA);
    const long TE = NT_MAIN + blockIdx.x;            // extra tile (wave0 only)

    // ---- 1. q per-lane loads first (oldest in vmcnt FIFO) ----
    const float4* s4 = (const float4*)s_emb;
    const float4* r4 = (const float4*)rel_emb;
    float4 sv[8], rv[8];
#pragma unroll
    for (int k = 0; k < 8; ++k) sv[k] = s4[k*64 + lane];
#pragma unroll
    for (int k = 0; k < 8; ++k) rv[k] = r4[k*64 + lane];

    auto dma8 = [&](long tile, char* l) {            // 8 x 1KB coalesced DMA
        const char* g = (const char*)emb_e + tile * 8192;
#pragma unroll
        for (int k = 0; k < 8; ++k) {
            const unsigned p = (unsigned)(k*1024 + lane*16);
            __builtin_amdgcn_global_load_lds((glb_vp*)(g + eswz(p)),
                                             (lds_vp*)(l + k*1024), 16, 0, 0);
        }
    };

    // ---- 2. e-DMA for tile T1 -> b1 (in flight during q work) ----
    dma8(T0 + 1, b1);

    // ---- 3. q = s + r -> b0 (swizzled), hi+lo bf16 fragments ----
#pragma unroll
    for (int k = 0; k < 8; ++k) {
        const unsigned p = (unsigned)(k*1024 + lane*16);
        float4 q = make_float4(sv[k].x+rv[k].x, sv[k].y+rv[k].y,
                               sv[k].z+rv[k].z, sv[k].w+rv[k].w);
        *(float4*)(b0 + eswz(p)) = q;
    }
    asm volatile("s_waitcnt lgkmcnt(0)" ::: "memory");

    const unsigned fb = (unsigned)(m*256 + h*32);
    bf16x8 qh[4], ql[4];
    float qn_part = 0.f;
#pragma unroll
    for (int tt = 0; tt < 4; ++tt) {
        const unsigned pe = eswz(fb + tt*64);
        float4 q0 = *(const float4*)(b0 + pe);
        float4 q1 = *(const float4*)(b0 + (pe ^ 16));
        const float qf[8] = {q0.x,q0.y,q0.z,q0.w, q1.x,q1.y,q1.z,q1.w};
#pragma unroll
        for (int i = 0; i < 8; ++i) {
            const float f = qf[i];
            qn_part = fmaf(f, f, qn_part);
            const unsigned u = __float_as_uint(f);
            qh[tt][i] = (short)(u >> 16);                          // trunc hi
            const float lo = f - __uint_as_float(u & 0xFFFF0000u); // exact
            ql[tt][i] = (short)(__float_as_uint(lo) >> 16);
        }
    }
    const float qn_own = qn_part + __shfl_xor(qn_part, 32);
    float qn_all[32];                      // readlane -> wave-uniform SGPRs
#pragma unroll
    for (int i = 0; i < 32; ++i)
        qn_all[i] = __uint_as_float(
            __builtin_amdgcn_readlane(__float_as_uint(qn_own), i));

    asm volatile("s_waitcnt lgkmcnt(0)" ::: "memory");  // q frag reads done
    dma8(T0 + 0, b0);                                   // FIFO: T1(8), T0(8)

    // ---- 4. compute (preds overwrite acc in place) ----
    auto compute_tile = [&](const char* L, f32x16& acc) {
#pragma unroll
        for (int i = 0; i < 16; ++i) acc[i] = 0.f;
        float en_part = 0.f;
#pragma unroll
        for (int tt = 0; tt < 4; ++tt) {
            const unsigned pe = eswz(fb + tt*64);
            float4 e0 = *(const float4*)(L + pe);
            float4 e1 = *(const float4*)(L + (pe ^ 16));
            en_part = fmaf(e0.x, e0.x, en_part);
            en_part = fmaf(e0.y, e0.y, en_part);
            en_part = fmaf(e0.z, e0.z, en_part);
            en_part = fmaf(e0.w, e0.w, en_part);
            en_part = fmaf(e1.x, e1.x, en_part);
            en_part = fmaf(e1.y, e1.y, en_part);
            en_part = fmaf(e1.z, e1.z, en_part);
            en_part = fmaf(e1.w, e1.w, en_part);
            u32x4 ep;
            ep[0] = __builtin_amdgcn_perm(__float_as_uint(e0.y),
                                          __float_as_uint(e0.x), 0x07060302u);
            ep[1] = __builtin_amdgcn_perm(__float_as_uint(e0.w),
                                          __float_as_uint(e0.z), 0x07060302u);
            ep[2] = __builtin_amdgcn_perm(__float_as_uint(e1.y),
                                          __float_as_uint(e1.x), 0x07060302u);
            ep[3] = __builtin_amdgcn_perm(__float_as_uint(e1.w),
                                          __float_as_uint(e1.z), 0x07060302u);
            const bf16x8 eh = __builtin_bit_cast(bf16x8, ep);
            acc = __builtin_amdgcn_mfma_f32_32x32x16_bf16(qh[tt], eh, acc, 0,0,0);
            acc = __builtin_amdgcn_mfma_f32_32x32x16_bf16(ql[tt], eh, acc, 0,0,0);
        }
        const float en = en_part + __shfl_xor(en_part, 32);
#pragma unroll
        for (int r = 0; r < 16; ++r) {
            const int bb = (r & 3) + 8*(r >> 2);
            const float qn_v = h ? qn_all[bb + 4] : qn_all[bb];
            const float d2 = fmaxf(fmaf(-2.f, acc[r], qn_v + en), 0.f);
            acc[r] = MARGIN - sqrtf(d2);
        }
    };

    f32x16 p0, p1, p2, p3, pE;
    asm volatile("s_waitcnt vmcnt(8)" ::: "memory");    // T1 done, T0 flying
    compute_tile(b1, p1);
    asm volatile("s_waitcnt lgkmcnt(0)" ::: "memory");  // b1 reads retired
    dma8(T0 + 2, b1);                                   // FIFO: T0, T2
    asm volatile("s_waitcnt vmcnt(8)" ::: "memory");    // T0 done, T2 flying
    compute_tile(b0, p0);
    asm volatile("s_waitcnt lgkmcnt(0)" ::: "memory");  // b0 reads retired
    dma8(T0 + 3, b0);                                   // FIFO: T2, T3
    if (hv) {                                           // 5-tile leg (wave0)
        asm volatile("s_waitcnt vmcnt(8)" ::: "memory");  // T2 done
        compute_tile(b1, p2);
        asm volatile("s_waitcnt lgkmcnt(0)" ::: "memory");
        dma8(TE, b1);                                     // FIFO: T3, TE
        asm volatile("s_waitcnt vmcnt(8)" ::: "memory");  // T3 done
        compute_tile(b0, p3);
        asm volatile("s_waitcnt vmcnt(0)" ::: "memory");  // TE done
        compute_tile(b1, pE);
    } else {
        asm volatile("s_waitcnt vmcnt(8)" ::: "memory");  // T2 done
        compute_tile(b1, p2);
        asm volatile("s_waitcnt vmcnt(0)" ::: "memory");  // T3 done
        compute_tile(b0, p3);
    }

    // ---- 5. preds -> oT [32][256] (+oE [32][32]) overlay, clean stores ----
    __syncthreads();                    // all waves done reading e-bufs
    float* oT = (float*)lds;
    float* oE = (float*)(lds + 32768);
    const int nlb = w*128 + m;
#pragma unroll
    for (int r = 0; r < 16; ++r) {
        const int b = (r & 3) + 8*(r >> 2) + 4*h;
        oT[b*256 + nlb +  0] = p0[r];
        oT[b*256 + nlb + 32] = p1[r];
        oT[b*256 + nlb + 64] = p2[r];
        oT[b*256 + nlb + 96] = p3[r];
        if (hv) oE[b*32 + m] = pE[r];
    }
    __syncthreads();

    const long nb = (long)blockIdx.x * 256;
#pragma unroll
    for (int k = 0; k < 16; ++k) {      // wave w: rows w*16..w*16+15, 1KB each
        const int  rb  = w*16 + k;
        const float4 v = *(const float4*)(oT + rb*256 + lane*4);
        *(float4*)(out + (size_t)rb * N + nb + lane*4) = v;
    }

    if (blockIdx.x < EXTRA) {           // extra tile: 128B/row, both waves
        const long ne = TE * 32;
#pragma unroll
        for (int k = 0; k < 2; ++k) {   // 8 rows per instr
            const int rb = w*16 + k*8 + (lane >> 3);
            const int c4 = (lane & 7) * 4;
            const float4 v = *(const float4*)(oE + rb*32 + c4);
            *(float4*)(out + (size_t)rb * N + ne + c4) = v;
        }
    }
}

extern "C" void kernel_launch(void* const* d_in, const int* in_sizes, int n_in,
                              void* d_out, int out_size, void* d_ws, size_t ws_size,
                              hipStream_t stream) {
    const float* s = (const float*)d_in[0];
    const float* r = (const float*)d_in[1];
    const float* e = (const float*)d_in[2];
    float* out = (float*)d_out;

    const int N = in_sizes[2] / 64;            // 200000
    transe14<<<768, 128, 0, stream>>>(s, r, e, out, N);
}